// Round 12
// baseline (90.761 us; speedup 1.0000x reference)
//
#include <hip/hip_runtime.h>
#include <hip/hip_bf16.h>

// Problem constants (SelfAttention_773094113877)
#define LSEQ 2048
#define NB   2
#define NH   16
#define HD   64
#define NKT  32                      // LSEQ / 64 key-tiles
// Q is pre-scaled by log2(e)/sqrt(EMBED) in proj; attn uses native exp2.
#define QSCALE 0.04508687049285173f

typedef __attribute__((ext_vector_type(8))) __bf16 bf16x8;
typedef __attribute__((ext_vector_type(4))) __bf16 bf16x4;
typedef __attribute__((ext_vector_type(2))) __bf16 bf16x2;
typedef __attribute__((ext_vector_type(4))) float  f32x4;

// ---------------- mask bit-pack: one wave per 64 keys ----------------
// Output TRANSPOSED: mbT[n][kt][q] so attn's per-tile loads are lane-coalesced.
__global__ __launch_bounds__(256)
void pack_mask_kernel(const int* __restrict__ mask,
                      unsigned long long* __restrict__ mbT) {
  size_t gw = ((size_t)blockIdx.x * 256 + threadIdx.x) >> 6;  // word index
  int lane = threadIdx.x & 63;
  int v = mask[gw * 64 + lane];
  unsigned long long b = __ballot(v != 0);
  if (lane == 0) {
    int kt = (int)(gw & (NKT - 1));        // gw = (n*LSEQ + q)*NKT + kt
    size_t nq = gw >> 5;
    int q = (int)(nq & (LSEQ - 1));
    int n = (int)(nq >> 11);
    mbT[((size_t)n * NKT + kt) * LSEQ + q] = b;
  }
}

// ---------------- per-head projection via MFMA (bf16 split-3) ----------------
// V output (z==0) is written TRANSPOSED + key-permuted + swizzle-baked:
//   Vtp[nh][kt][d][col]: content(col) = V[key(col ^ (swzV(d)<<3))][d]
//   key(c) = (c&32) | ((c&4)<<2) | ((c&24)>>1) | (c&3)   (inverse of kslot)
__global__ __launch_bounds__(256)
void proj_kernel(const float* __restrict__ xv, const float* __restrict__ Wv_,
                 const float* __restrict__ xk, const float* __restrict__ Wk_,
                 const float* __restrict__ xq, const float* __restrict__ Wq_,
                 __bf16* __restrict__ outv, __bf16* __restrict__ outk,
                 __bf16* __restrict__ outq) {
  __shared__ __bf16 S[16384];          // 32 KB: Xh|Xl|Wh|Wl; tb aliases Xh/Xl
  __bf16* Xh = S;
  __bf16* Xl = S + 4096;
  __bf16* Wh = S + 8192;
  __bf16* Wl = S + 12288;

  const float* x; const float* W; __bf16* out;
  if (blockIdx.z == 0)      { x = xv; W = Wv_; out = outv; }
  else if (blockIdx.z == 1) { x = xk; W = Wk_; out = outk; }
  else                      { x = xq; W = Wq_; out = outq; }
  const float osc = (blockIdx.z == 2) ? QSCALE : 1.0f;

  const int tid = threadIdx.x;
  const int bx = blockIdx.x;
  const int h  = blockIdx.y;
  const int n  = bx >> 5;
  const int l0 = (bx & 31) << 6;

  const int r  = tid >> 2;
  const int c0 = (tid & 3) << 4;
  const float* xrow = x + ((size_t)(n * LSEQ + l0) + r) * 1024 + h * 64 + c0;
  const float* wrow = W + r * 64 + c0;

#pragma unroll
  for (int hf = 0; hf < 2; ++hf) {
    int kc = c0 + hf * 8;
    int off = r * 64 + (kc ^ ((r & 7) << 3));
    float4 a = *(const float4*)(xrow + hf * 8);
    float4 b = *(const float4*)(xrow + hf * 8 + 4);
    float va[8] = {a.x, a.y, a.z, a.w, b.x, b.y, b.z, b.w};
    bf16x8 hi, lo;
#pragma unroll
    for (int j = 0; j < 8; ++j) {
      __bf16 h_ = (__bf16)va[j];
      hi[j] = h_;
      lo[j] = (__bf16)(va[j] - (float)h_);
    }
    *(bf16x8*)(Xh + off) = hi;
    *(bf16x8*)(Xl + off) = lo;

    float4 c = *(const float4*)(wrow + hf * 8);
    float4 d = *(const float4*)(wrow + hf * 8 + 4);
    float vw[8] = {c.x, c.y, c.z, c.w, d.x, d.y, d.z, d.w};
    bf16x8 whv, wlv;
#pragma unroll
    for (int j = 0; j < 8; ++j) {
      __bf16 h_ = (__bf16)vw[j];
      whv[j] = h_;
      wlv[j] = (__bf16)(vw[j] - (float)h_);
    }
    *(bf16x8*)(Wh + off) = whv;
    *(bf16x8*)(Wl + off) = wlv;
  }
  __syncthreads();

  const int wv   = tid >> 6;
  const int lane = tid & 63;
  const int l15  = lane & 15;
  const int lhi  = lane >> 4;

  bf16x8 xhf[2], xlf[2];
  const int arow = wv * 16 + l15;
#pragma unroll
  for (int ko = 0; ko < 2; ++ko) {
    int aoff = arow * 64 + ((ko * 32 + lhi * 8) ^ ((arow & 7) << 3));
    xhf[ko] = *(const bf16x8*)(Xh + aoff);
    xlf[ko] = *(const bf16x8*)(Xl + aoff);
  }

  f32x4 acc[4] = {};
#pragma unroll
  for (int cg = 0; cg < 4; ++cg) {
    int d = cg * 16 + l15;
#pragma unroll
    for (int ko = 0; ko < 2; ++ko) {
      int boff = d * 64 + ((ko * 32 + lhi * 8) ^ ((d & 7) << 3));
      bf16x8 whf = *(const bf16x8*)(Wh + boff);
      bf16x8 wlf = *(const bf16x8*)(Wl + boff);
      acc[cg] = __builtin_amdgcn_mfma_f32_16x16x32_bf16(xhf[ko], whf, acc[cg], 0, 0, 0);
      acc[cg] = __builtin_amdgcn_mfma_f32_16x16x32_bf16(xhf[ko], wlf, acc[cg], 0, 0, 0);
      acc[cg] = __builtin_amdgcn_mfma_f32_16x16x32_bf16(xlf[ko], whf, acc[cg], 0, 0, 0);
    }
  }
  __syncthreads();

  __bf16* tb = S;                      // [64][72] = [token(key-in-tile)][d]
#pragma unroll
  for (int cg = 0; cg < 4; ++cg)
#pragma unroll
    for (int rr = 0; rr < 4; ++rr)
      tb[(wv * 16 + lhi * 4 + rr) * 72 + cg * 16 + l15] = (__bf16)(acc[cg][rr] * osc);
  __syncthreads();

  if (blockIdx.z == 0) {
    // ---- V: transposed + permuted + swizzle-baked stores ----
    const int d   = tid >> 2;
    const int cg  = tid & 3;
    const int swz = (d & 7) ^ ((d >> 3) & 7);
    __bf16* vout = out + (size_t)(n * NH + h) * (LSEQ * HD)
                 + (size_t)(bx & 31) * 4096 + d * 64 + cg * 16;
    bf16x8 s0, s1;
#pragma unroll
    for (int j = 0; j < 16; ++j) {
      int c  = cg * 16 + j;
      int cx = c ^ (swz << 3);
      int key = (cx & 32) | ((cx & 4) << 2) | ((cx & 24) >> 1) | (cx & 3);
      __bf16 v_ = tb[key * 72 + d];
      if (j < 8) s0[j] = v_; else s1[j - 8] = v_;
    }
    *(bf16x8*)(vout)     = s0;
    *(bf16x8*)(vout + 8) = s1;
  } else {
    const int tok = tid >> 2;
    const int d0  = (tid & 3) * 16;
    bf16x8 o0 = *(const bf16x8*)(tb + tok * 72 + d0);
    bf16x8 o1 = *(const bf16x8*)(tb + tok * 72 + d0 + 8);
    size_t ob = (size_t)(n * NH + h) * LSEQ + l0;
    *(bf16x8*)(out + (ob + tok) * HD + d0)     = o0;
    *(bf16x8*)(out + (ob + tok) * HD + d0 + 8) = o1;
  }
}

// ---------------- fused flash attention ----------------
// grid (16, 32) = 512 blocks, 512 threads = 8 waves.
// K-split: wave = (hw, wq); hw = key-half, wq = q-row group (32 rows).
// hw=1 waves stage K, hw=0 stage V — both via global_load_lds.
// 4 K bufs + 4 V bufs (64 KB), ONE barrier per TWO tiles; the 2-period loop
// is unrolled so ALL buffer indices are compile-time (imm-offset ds_reads).
// Register-P via key-permuted V columns; lsum via MFMA with B=ones.
__global__ __launch_bounds__(512, 4)
void attn_kernel(const __bf16* __restrict__ Qb, const __bf16* __restrict__ Kb,
                 const __bf16* __restrict__ Vtp,
                 const unsigned long long* __restrict__ mbT,
                 float* __restrict__ out) {
  __shared__ __bf16 KV[32768];   // K bufs 0-3 @ b*4096 ; V bufs 0-3 @ 16384+b*4096
  __shared__ float  Ls[128];     // partial lsum exchange

  const int tid  = threadIdx.x;
  const int wid  = tid >> 6;
  const int hw   = wid >> 2;           // key-half (0/1)
  const int wq   = wid & 3;            // q-row group
  const int lane = tid & 63;
  const int l15  = lane & 15;
  const int lhi  = lane >> 4;

  // XCD-bijective swizzle: 64 blocks/XCD = 4 heads x 16 q-tiles per XCD
  const int lin = blockIdx.y * 16 + blockIdx.x;    // 0..511
  const int xcd = lin & 7;
  const int idx = lin >> 3;                        // 0..63
  const int nh  = xcd + ((idx >> 4) << 3);
  const int qt  = idx & 15;
  const int n   = nh >> 4;
  const int h   = nh & 15;
  const int q0  = qt << 7;                         // 128 q-rows per block

  const __bf16* Qg = Qb + ((size_t)nh * LSEQ + q0) * HD;
  const __bf16* Kg = Kb + (size_t)nh * LSEQ * HD;
  const __bf16* Vg = Vtp + (size_t)nh * LSEQ * HD;   // [kt][d][col]

  // Q in regs (pre-scaled): qrow = wq*32 + mi*16 + l15, dims ks*32 + lhi*8..+7
  bf16x8 qf[2][2];
#pragma unroll
  for (int mi = 0; mi < 2; ++mi)
#pragma unroll
    for (int ks = 0; ks < 2; ++ks)
      qf[mi][ks] = *(const bf16x8*)(Qg + (size_t)(wq * 32 + mi * 16 + l15) * HD
                                       + ks * 32 + lhi * 8);

  f32x4 o[2][4] = {};
  f32x4 o_ls[2] = {};
  // transposed mask: mrow[kt*LSEQ] = word for (qrow=q0+wq*32+l15, tile kt)
  const unsigned long long* mrow =
      mbT + (size_t)n * NKT * LSEQ + q0 + wq * 32 + l15;

  bf16x8 onesf;
#pragma unroll
  for (int j = 0; j < 8; ++j) onesf[j] = (__bf16)1.0f;

#define STAGE_K(kt_, buf_)                                                         \
  _Pragma("unroll")                                                                \
  for (int it = 0; it < 2; ++it) {                                                 \
    int chb = wq * 64 + it * 256;                                                  \
    int ch = chb + lane;                                                           \
    int skey = ch >> 3, sdc = ch & 7;                                              \
    const __bf16* src = Kg + (size_t)(kt_) * 4096 + skey * 64 + ((sdc ^ (skey & 7)) << 3); \
    __builtin_amdgcn_global_load_lds(                                              \
        (const __attribute__((address_space(1))) void*)src,                        \
        (__attribute__((address_space(3))) void*)(KV + (buf_) * 4096 + chb * 8), 16, 0, 0); \
  }
#define STAGE_V(kt_, buf_)                                                         \
  _Pragma("unroll")                                                                \
  for (int it = 0; it < 2; ++it) {                                                 \
    int chb = wq * 64 + it * 256;                                                  \
    int ch = chb + lane;                                                           \
    const __bf16* src = Vg + (size_t)(kt_) * 4096 + ch * 8;                        \
    __builtin_amdgcn_global_load_lds(                                              \
        (const __attribute__((address_space(1))) void*)src,                        \
        (__attribute__((address_space(3))) void*)(KV + 16384 + (buf_) * 4096 + chb * 8), 16, 0, 0); \
  }

// compute one 64-key tile from K/V buffer cb_ (cb_ MUST be compile-time)
#define COMPUTE(W0_, W1_, cb_)                                                     \
  {                                                                                \
    const __bf16* Kc = KV + (cb_) * 4096;                                          \
    f32x4 s[2][2] = {};                                                            \
    _Pragma("unroll")                                                              \
    for (int ks = 0; ks < 2; ++ks)                                                 \
      _Pragma("unroll")                                                            \
      for (int t = 0; t < 2; ++t) {                                                \
        int key = hw * 32 + t * 16 + l15;                                          \
        bf16x8 kf = *(const bf16x8*)(                                              \
            Kc + key * 64 + ((ks * 32 + lhi * 8) ^ ((key & 7) << 3)));             \
        s[0][t] = __builtin_amdgcn_mfma_f32_16x16x32_bf16(kf, qf[0][ks], s[0][t], 0, 0, 0); \
        s[1][t] = __builtin_amdgcn_mfma_f32_16x16x32_bf16(kf, qf[1][ks], s[1][t], 0, 0, 0); \
      }                                                                            \
    bf16x8 pa[2];                                                                  \
    _Pragma("unroll")                                                              \
    for (int mi = 0; mi < 2; ++mi) {                                               \
      unsigned long long w = mi ? (W1_) : (W0_);                                   \
      unsigned shl = (unsigned)(w >> (hw * 32 + lhi * 4));                         \
      _Pragma("unroll")                                                            \
      for (int t = 0; t < 2; ++t)                                                  \
        _Pragma("unroll")                                                          \
        for (int r = 0; r < 4; ++r) {                                              \
          float p = __builtin_amdgcn_exp2f(s[mi][t][r]);                           \
          p = ((shl >> (t * 16 + r)) & 1u) ? p : 0.f;                              \
          pa[mi][t * 4 + r] = (__bf16)p;                                           \
        }                                                                          \
    }                                                                              \
    const __bf16* Vc = KV + 16384 + (cb_) * 4096;                                  \
    _Pragma("unroll")                                                              \
    for (int t = 0; t < 4; ++t) {                                                  \
      int d = t * 16 + l15;                                                        \
      int swz = (d & 7) ^ ((d >> 3) & 7);                                          \
      bf16x8 vf = *(const bf16x8*)(                                                \
          Vc + d * 64 + ((hw * 32 + lhi * 8) ^ (swz << 3)));                       \
      o[0][t] = __builtin_amdgcn_mfma_f32_16x16x32_bf16(pa[0], vf, o[0][t], 0, 0, 0); \
      o[1][t] = __builtin_amdgcn_mfma_f32_16x16x32_bf16(pa[1], vf, o[1][t], 0, 0, 0); \
    }                                                                              \
    o_ls[0] = __builtin_amdgcn_mfma_f32_16x16x32_bf16(pa[0], onesf, o_ls[0], 0, 0, 0); \
    o_ls[1] = __builtin_amdgcn_mfma_f32_16x16x32_bf16(pa[1], onesf, o_ls[1], 0, 0, 0); \
  }

#define MASKLD(kt_, a_, b_)                                                        \
  a_ = mrow[(size_t)(kt_) * LSEQ]; b_ = mrow[(size_t)(kt_) * LSEQ + 16];

  // prologue: tiles 0,1 -> bufs 0,1
  if (hw == 1) { STAGE_K(0, 0); STAGE_K(1, 1); }
  else         { STAGE_V(0, 0); STAGE_V(1, 1); }
  unsigned long long wA0, wA1, wB0, wB1;
  MASKLD(0, wA0, wA1);
  MASKLD(1, wB0, wB1);
  __syncthreads();

  for (int pp = 0; pp < 8; ++pp) {
    unsigned long long nA0 = 0, nA1 = 0, nB0 = 0, nB1 = 0;
    // phase A: compute tiles 4pp,4pp+1 from bufs 0,1; stage 4pp+2,4pp+3 -> bufs 2,3
    if (hw == 1) { STAGE_K(4 * pp + 2, 2); STAGE_K(4 * pp + 3, 3); }
    else         { STAGE_V(4 * pp + 2, 2); STAGE_V(4 * pp + 3, 3); }
    MASKLD(4 * pp + 2, nA0, nA1);
    MASKLD(4 * pp + 3, nB0, nB1);
    COMPUTE(wA0, wA1, 0);
    COMPUTE(wB0, wB1, 1);
    wA0 = nA0; wA1 = nA1; wB0 = nB0; wB1 = nB1;
    __syncthreads();
    // phase B: compute tiles 4pp+2,4pp+3 from bufs 2,3; stage 4pp+4,4pp+5 -> bufs 0,1
    nA0 = nA1 = nB0 = nB1 = 0;
    if (pp < 7) {
      if (hw == 1) { STAGE_K(4 * pp + 4, 0); STAGE_K(4 * pp + 5, 1); }
      else         { STAGE_V(4 * pp + 4, 0); STAGE_V(4 * pp + 5, 1); }
      MASKLD(4 * pp + 4, nA0, nA1);
      MASKLD(4 * pp + 5, nB0, nB1);
    }
    COMPUTE(wA0, wA1, 2);
    COMPUTE(wB0, wB1, 3);
    wA0 = nA0; wA1 = nA1; wB0 = nB0; wB1 = nB1;
    __syncthreads();
  }

  // ---- combine halves: hw=1 dumps partials, hw=0 adds + stores ----
  float* Sf = (float*)KV;              // 8192 floats = 32 KB (K-buf region)
  if (hw == 1) {
#pragma unroll
    for (int mi = 0; mi < 2; ++mi) {
#pragma unroll
      for (int t = 0; t < 4; ++t)
        *(f32x4*)&Sf[wq * 2048 + (mi * 4 + t) * 256 + lane * 4] = o[mi][t];
      if (l15 == 0)
        *(f32x4*)&Ls[wq * 32 + mi * 16 + lhi * 4] = o_ls[mi];
    }
  }
  __syncthreads();
  if (hw == 0) {
#pragma unroll
    for (int mi = 0; mi < 2; ++mi) {
      f32x4 pls = *(const f32x4*)&Ls[wq * 32 + mi * 16 + lhi * 4];
      float inv[4];
#pragma unroll
      for (int r = 0; r < 4; ++r)
        inv[r] = 1.f / (o_ls[mi][r] + pls[r]);
#pragma unroll
      for (int t = 0; t < 4; ++t) {
        f32x4 po = *(const f32x4*)&Sf[wq * 2048 + (mi * 4 + t) * 256 + lane * 4];
#pragma unroll
        for (int r = 0; r < 4; ++r) {
          size_t ob = ((size_t)n * LSEQ + q0 + wq * 32 + mi * 16 + lhi * 4 + r) * 1024
                    + h * 64 + t * 16 + l15;
          out[ob] = (o[mi][t][r] + po[r]) * inv[r];
        }
      }
    }
  }
#undef STAGE_K
#undef STAGE_V
#undef COMPUTE
#undef MASKLD
}

extern "C" void kernel_launch(void* const* d_in, const int* in_sizes, int n_in,
                              void* d_out, int out_size, void* d_ws, size_t ws_size,
                              hipStream_t stream) {
  const float* xv   = (const float*)d_in[0];   // values
  const float* xk   = (const float*)d_in[1];   // keys
  const float* xq   = (const float*)d_in[2];   // queries
  const int*   mask = (const int*)d_in[3];
  const float* Wv   = (const float*)d_in[4];
  const float* Wk   = (const float*)d_in[5];
  const float* Wq   = (const float*)d_in[6];
  float* out = (float*)d_out;

  const size_t elems = (size_t)NB * NH * LSEQ * HD;       // 4,194,304
  __bf16* Qw = (__bf16*)d_ws;
  __bf16* Kw = Qw + elems;
  __bf16* Vw = Kw + elems;          // holds permuted/transposed Vtp layout
  unsigned long long* mb = (unsigned long long*)(Vw + elems);  // 1 MB

  pack_mask_kernel<<<dim3(NB * LSEQ * NKT / 4), 256, 0, stream>>>(mask, mb);
  proj_kernel<<<dim3(64, NH, 3), 256, 0, stream>>>(xv, Wv, xk, Wk, xq, Wq,
                                                   Vw, Kw, Qw);
  attn_kernel<<<dim3(16, 32), 512, 0, stream>>>(Qw, Kw, Vw, mb, out);
}

// Round 13
// 86.902 us; speedup vs baseline: 1.0444x; 1.0444x over previous
//
#include <hip/hip_runtime.h>
#include <hip/hip_bf16.h>

// Problem constants (SelfAttention_773094113877)
#define LSEQ 2048
#define NB   2
#define NH   16
#define HD   64
#define NKT  32                      // LSEQ / 64 key-tiles
// Q is pre-scaled by log2(e)/sqrt(EMBED) in proj; attn uses native exp2.
#define QSCALE 0.04508687049285173f

typedef __attribute__((ext_vector_type(8))) __bf16 bf16x8;
typedef __attribute__((ext_vector_type(4))) __bf16 bf16x4;
typedef __attribute__((ext_vector_type(2))) __bf16 bf16x2;
typedef __attribute__((ext_vector_type(4))) float  f32x4;

// ---------------- mask bit-pack: one wave per 64 keys ----------------
__global__ __launch_bounds__(256)
void pack_mask_kernel(const int* __restrict__ mask,
                      unsigned long long* __restrict__ mbits) {
  size_t gw = ((size_t)blockIdx.x * 256 + threadIdx.x) >> 6;  // word index
  int lane = threadIdx.x & 63;
  int v = mask[gw * 64 + lane];
  unsigned long long b = __ballot(v != 0);
  if (lane == 0) mbits[gw] = b;
}

// ---------------- per-head projection via MFMA (bf16 split-3) ----------------
// V output (z==0) is written TRANSPOSED + key-permuted + swizzle-baked:
//   Vtp[nh][kt][d][col]: content(col) = V[key(col ^ (swzV(d)<<3))][d]
//   key(c) = (c&32) | ((c&4)<<2) | ((c&24)>>1) | (c&3)   (inverse of kslot)
__global__ __launch_bounds__(256)
void proj_kernel(const float* __restrict__ xv, const float* __restrict__ Wv_,
                 const float* __restrict__ xk, const float* __restrict__ Wk_,
                 const float* __restrict__ xq, const float* __restrict__ Wq_,
                 __bf16* __restrict__ outv, __bf16* __restrict__ outk,
                 __bf16* __restrict__ outq) {
  __shared__ __bf16 S[16384];          // 32 KB: Xh|Xl|Wh|Wl; tb aliases Xh/Xl
  __bf16* Xh = S;
  __bf16* Xl = S + 4096;
  __bf16* Wh = S + 8192;
  __bf16* Wl = S + 12288;

  const float* x; const float* W; __bf16* out;
  if (blockIdx.z == 0)      { x = xv; W = Wv_; out = outv; }
  else if (blockIdx.z == 1) { x = xk; W = Wk_; out = outk; }
  else                      { x = xq; W = Wq_; out = outq; }
  const float osc = (blockIdx.z == 2) ? QSCALE : 1.0f;

  const int tid = threadIdx.x;
  const int bx = blockIdx.x;
  const int h  = blockIdx.y;
  const int n  = bx >> 5;
  const int l0 = (bx & 31) << 6;

  const int r  = tid >> 2;
  const int c0 = (tid & 3) << 4;
  const float* xrow = x + ((size_t)(n * LSEQ + l0) + r) * 1024 + h * 64 + c0;
  const float* wrow = W + r * 64 + c0;

#pragma unroll
  for (int hf = 0; hf < 2; ++hf) {
    int kc = c0 + hf * 8;
    int off = r * 64 + (kc ^ ((r & 7) << 3));
    float4 a = *(const float4*)(xrow + hf * 8);
    float4 b = *(const float4*)(xrow + hf * 8 + 4);
    float va[8] = {a.x, a.y, a.z, a.w, b.x, b.y, b.z, b.w};
    bf16x8 hi, lo;
#pragma unroll
    for (int j = 0; j < 8; ++j) {
      __bf16 h_ = (__bf16)va[j];
      hi[j] = h_;
      lo[j] = (__bf16)(va[j] - (float)h_);
    }
    *(bf16x8*)(Xh + off) = hi;
    *(bf16x8*)(Xl + off) = lo;

    float4 c = *(const float4*)(wrow + hf * 8);
    float4 d = *(const float4*)(wrow + hf * 8 + 4);
    float vw[8] = {c.x, c.y, c.z, c.w, d.x, d.y, d.z, d.w};
    bf16x8 whv, wlv;
#pragma unroll
    for (int j = 0; j < 8; ++j) {
      __bf16 h_ = (__bf16)vw[j];
      whv[j] = h_;
      wlv[j] = (__bf16)(vw[j] - (float)h_);
    }
    *(bf16x8*)(Wh + off) = whv;
    *(bf16x8*)(Wl + off) = wlv;
  }
  __syncthreads();

  const int wv   = tid >> 6;
  const int lane = tid & 63;
  const int l15  = lane & 15;
  const int lhi  = lane >> 4;

  bf16x8 xhf[2], xlf[2];
  const int arow = wv * 16 + l15;
#pragma unroll
  for (int ko = 0; ko < 2; ++ko) {
    int aoff = arow * 64 + ((ko * 32 + lhi * 8) ^ ((arow & 7) << 3));
    xhf[ko] = *(const bf16x8*)(Xh + aoff);
    xlf[ko] = *(const bf16x8*)(Xl + aoff);
  }

  f32x4 acc[4] = {};
#pragma unroll
  for (int cg = 0; cg < 4; ++cg) {
    int d = cg * 16 + l15;
#pragma unroll
    for (int ko = 0; ko < 2; ++ko) {
      int boff = d * 64 + ((ko * 32 + lhi * 8) ^ ((d & 7) << 3));
      bf16x8 whf = *(const bf16x8*)(Wh + boff);
      bf16x8 wlf = *(const bf16x8*)(Wl + boff);
      acc[cg] = __builtin_amdgcn_mfma_f32_16x16x32_bf16(xhf[ko], whf, acc[cg], 0, 0, 0);
      acc[cg] = __builtin_amdgcn_mfma_f32_16x16x32_bf16(xhf[ko], wlf, acc[cg], 0, 0, 0);
      acc[cg] = __builtin_amdgcn_mfma_f32_16x16x32_bf16(xlf[ko], whf, acc[cg], 0, 0, 0);
    }
  }
  __syncthreads();

  __bf16* tb = S;                      // [64][72] = [token(key-in-tile)][d]
#pragma unroll
  for (int cg = 0; cg < 4; ++cg)
#pragma unroll
    for (int rr = 0; rr < 4; ++rr)
      tb[(wv * 16 + lhi * 4 + rr) * 72 + cg * 16 + l15] = (__bf16)(acc[cg][rr] * osc);
  __syncthreads();

  if (blockIdx.z == 0) {
    // ---- V: transposed + permuted + swizzle-baked stores ----
    const int d   = tid >> 2;
    const int cg  = tid & 3;
    const int swz = (d & 7) ^ ((d >> 3) & 7);
    __bf16* vout = out + (size_t)(n * NH + h) * (LSEQ * HD)
                 + (size_t)(bx & 31) * 4096 + d * 64 + cg * 16;
    bf16x8 s0, s1;
#pragma unroll
    for (int j = 0; j < 16; ++j) {
      int c  = cg * 16 + j;
      int cx = c ^ (swz << 3);
      int key = (cx & 32) | ((cx & 4) << 2) | ((cx & 24) >> 1) | (cx & 3);
      __bf16 v_ = tb[key * 72 + d];
      if (j < 8) s0[j] = v_; else s1[j - 8] = v_;
    }
    *(bf16x8*)(vout)     = s0;
    *(bf16x8*)(vout + 8) = s1;
  } else {
    const int tok = tid >> 2;
    const int d0  = (tid & 3) * 16;
    bf16x8 o0 = *(const bf16x8*)(tb + tok * 72 + d0);
    bf16x8 o1 = *(const bf16x8*)(tb + tok * 72 + d0 + 8);
    size_t ob = (size_t)(n * NH + h) * LSEQ + l0;
    *(bf16x8*)(out + (ob + tok) * HD + d0)     = o0;
    *(bf16x8*)(out + (ob + tok) * HD + d0 + 8) = o1;
  }
}

// ---------------- fused flash attention ----------------
// grid (16, 32) = 512 blocks, 512 threads = 8 waves.
// K-split: wave = (hw, wq); hw = key-half, wq = q-row group (32 rows).
// hw=1 waves stage K, hw=0 stage V — both via global_load_lds.
// 4 K bufs + 4 V bufs (64 KB), ONE barrier per TWO tiles (R11 structure).
// Per-period ILP: QK(A), QK(B) issued back-to-back, then SM(A)|PV(A)|SM(B)|PV(B)
// so softmax VALU overlaps the other tile's MFMA shadow (phase de-serialization).
// Register-P via key-permuted V columns; lsum via MFMA with B=ones.
__global__ __launch_bounds__(512, 4)
void attn_kernel(const __bf16* __restrict__ Qb, const __bf16* __restrict__ Kb,
                 const __bf16* __restrict__ Vtp,
                 const unsigned long long* __restrict__ mbits,
                 float* __restrict__ out) {
  __shared__ __bf16 KV[32768];   // K bufs 0-3 @ b*4096 ; V bufs 0-3 @ 16384+b*4096
  __shared__ float  Ls[128];     // partial lsum exchange

  const int tid  = threadIdx.x;
  const int wid  = tid >> 6;
  const int hw   = wid >> 2;           // key-half (0/1)
  const int wq   = wid & 3;            // q-row group
  const int lane = tid & 63;
  const int l15  = lane & 15;
  const int lhi  = lane >> 4;

  // XCD-bijective swizzle: 64 blocks/XCD = 4 heads x 16 q-tiles per XCD
  const int lin = blockIdx.y * 16 + blockIdx.x;    // 0..511
  const int xcd = lin & 7;
  const int idx = lin >> 3;                        // 0..63
  const int nh  = xcd + ((idx >> 4) << 3);
  const int qt  = idx & 15;
  const int n   = nh >> 4;
  const int h   = nh & 15;
  const int q0  = qt << 7;                         // 128 q-rows per block

  const __bf16* Qg = Qb + ((size_t)nh * LSEQ + q0) * HD;
  const __bf16* Kg = Kb + (size_t)nh * LSEQ * HD;
  const __bf16* Vg = Vtp + (size_t)nh * LSEQ * HD;   // [kt][d][col]

  // Q in regs (pre-scaled): qrow = wq*32 + mi*16 + l15, dims ks*32 + lhi*8..+7
  bf16x8 qf[2][2];
#pragma unroll
  for (int mi = 0; mi < 2; ++mi)
#pragma unroll
    for (int ks = 0; ks < 2; ++ks)
      qf[mi][ks] = *(const bf16x8*)(Qg + (size_t)(wq * 32 + mi * 16 + l15) * HD
                                       + ks * 32 + lhi * 8);

  f32x4 o[2][4] = {};
  f32x4 o_ls[2] = {};
  const unsigned long long* mrow0 =
      mbits + ((size_t)n * LSEQ + q0 + wq * 32 + l15) * NKT;
  const unsigned long long* mrow1 = mrow0 + (size_t)16 * NKT;

  bf16x8 onesf;
#pragma unroll
  for (int j = 0; j < 8; ++j) onesf[j] = (__bf16)1.0f;

#define STAGE_K(kt_, buf_)                                                         \
  _Pragma("unroll")                                                                \
  for (int it = 0; it < 2; ++it) {                                                 \
    int chb = wq * 64 + it * 256;                                                  \
    int ch = chb + lane;                                                           \
    int skey = ch >> 3, sdc = ch & 7;                                              \
    const __bf16* src = Kg + (size_t)(kt_) * 4096 + skey * 64 + ((sdc ^ (skey & 7)) << 3); \
    __builtin_amdgcn_global_load_lds(                                              \
        (const __attribute__((address_space(1))) void*)src,                        \
        (__attribute__((address_space(3))) void*)(KV + (buf_) * 4096 + chb * 8), 16, 0, 0); \
  }
#define STAGE_V(kt_, buf_)                                                         \
  _Pragma("unroll")                                                                \
  for (int it = 0; it < 2; ++it) {                                                 \
    int chb = wq * 64 + it * 256;                                                  \
    int ch = chb + lane;                                                           \
    const __bf16* src = Vg + (size_t)(kt_) * 4096 + ch * 8;                        \
    __builtin_amdgcn_global_load_lds(                                              \
        (const __attribute__((address_space(1))) void*)src,                        \
        (__attribute__((address_space(3))) void*)(KV + 16384 + (buf_) * 4096 + chb * 8), 16, 0, 0); \
  }

// ---- split per-tile phases (register-independent across A/B tiles) ----
#define QK_TILE(cb_, s_)                                                           \
  {                                                                                \
    const __bf16* Kc = KV + (cb_) * 4096;                                          \
    _Pragma("unroll")                                                              \
    for (int ks = 0; ks < 2; ++ks)                                                 \
      _Pragma("unroll")                                                            \
      for (int t = 0; t < 2; ++t) {                                                \
        int key = hw * 32 + t * 16 + l15;                                          \
        bf16x8 kf = *(const bf16x8*)(                                              \
            Kc + key * 64 + ((ks * 32 + lhi * 8) ^ ((key & 7) << 3)));             \
        s_[0][t] = __builtin_amdgcn_mfma_f32_16x16x32_bf16(kf, qf[0][ks], s_[0][t], 0, 0, 0); \
        s_[1][t] = __builtin_amdgcn_mfma_f32_16x16x32_bf16(kf, qf[1][ks], s_[1][t], 0, 0, 0); \
      }                                                                            \
  }
#define SM_TILE(s_, W0_, W1_, pa_)                                                 \
  {                                                                                \
    _Pragma("unroll")                                                              \
    for (int mi = 0; mi < 2; ++mi) {                                               \
      unsigned long long w = mi ? (W1_) : (W0_);                                   \
      unsigned shl = (unsigned)(w >> (hw * 32 + lhi * 4));                         \
      _Pragma("unroll")                                                            \
      for (int t = 0; t < 2; ++t)                                                  \
        _Pragma("unroll")                                                          \
        for (int r = 0; r < 4; ++r) {                                              \
          float p = __builtin_amdgcn_exp2f(s_[mi][t][r]);                          \
          p = ((shl >> (t * 16 + r)) & 1u) ? p : 0.f;                              \
          pa_[mi][t * 4 + r] = (__bf16)p;                                          \
        }                                                                          \
    }                                                                              \
  }
#define PV_TILE(pa_, cb_)                                                          \
  {                                                                                \
    const __bf16* Vc = KV + 16384 + (cb_) * 4096;                                  \
    _Pragma("unroll")                                                              \
    for (int t = 0; t < 4; ++t) {                                                  \
      int d = t * 16 + l15;                                                        \
      int swz = (d & 7) ^ ((d >> 3) & 7);                                          \
      bf16x8 vf = *(const bf16x8*)(                                                \
          Vc + d * 64 + ((hw * 32 + lhi * 8) ^ (swz << 3)));                       \
      o[0][t] = __builtin_amdgcn_mfma_f32_16x16x32_bf16(pa_[0], vf, o[0][t], 0, 0, 0); \
      o[1][t] = __builtin_amdgcn_mfma_f32_16x16x32_bf16(pa_[1], vf, o[1][t], 0, 0, 0); \
    }                                                                              \
    o_ls[0] = __builtin_amdgcn_mfma_f32_16x16x32_bf16(pa_[0], onesf, o_ls[0], 0, 0, 0); \
    o_ls[1] = __builtin_amdgcn_mfma_f32_16x16x32_bf16(pa_[1], onesf, o_ls[1], 0, 0, 0); \
  }

  // prologue: tiles 0,1 -> bufs 0,1
  if (hw == 1) { STAGE_K(0, 0); STAGE_K(1, 1); }
  else         { STAGE_V(0, 0); STAGE_V(1, 1); }
  unsigned long long wA0 = mrow0[0], wA1 = mrow1[0];
  unsigned long long wB0 = mrow0[1], wB1 = mrow1[1];
  __syncthreads();

  for (int p = 0; p < 16; ++p) {
    const int ca = (p & 1) << 1;         // compute bufs {ca, ca+1}
    const int na = ca ^ 2;               // stage bufs   {na, na+1}
    unsigned long long nA0 = 0, nA1 = 0, nB0 = 0, nB1 = 0;
    if (p < 15) {
      if (hw == 1) { STAGE_K(2 * p + 2, na); STAGE_K(2 * p + 3, na + 1); }
      else         { STAGE_V(2 * p + 2, na); STAGE_V(2 * p + 3, na + 1); }
      nA0 = mrow0[2 * p + 2]; nA1 = mrow1[2 * p + 2];
      nB0 = mrow0[2 * p + 3]; nB1 = mrow1[2 * p + 3];
    }
    // interleaved pair: QK(A), QK(B) back-to-back; SM overlaps other tile's MFMA
    f32x4 sA[2][2] = {}, sB[2][2] = {};
    bf16x8 paA[2], paB[2];
    QK_TILE(ca, sA);
    QK_TILE(ca + 1, sB);
    SM_TILE(sA, wA0, wA1, paA);
    PV_TILE(paA, ca);
    SM_TILE(sB, wB0, wB1, paB);
    PV_TILE(paB, ca + 1);
    wA0 = nA0; wA1 = nA1; wB0 = nB0; wB1 = nB1;
    __syncthreads();
  }

  // ---- combine halves: hw=1 dumps partials, hw=0 adds + stores ----
  float* Sf = (float*)KV;              // 8192 floats = 32 KB (K-buf region)
  if (hw == 1) {
#pragma unroll
    for (int mi = 0; mi < 2; ++mi) {
#pragma unroll
      for (int t = 0; t < 4; ++t)
        *(f32x4*)&Sf[wq * 2048 + (mi * 4 + t) * 256 + lane * 4] = o[mi][t];
      if (l15 == 0)
        *(f32x4*)&Ls[wq * 32 + mi * 16 + lhi * 4] = o_ls[mi];
    }
  }
  __syncthreads();
  if (hw == 0) {
#pragma unroll
    for (int mi = 0; mi < 2; ++mi) {
      f32x4 pls = *(const f32x4*)&Ls[wq * 32 + mi * 16 + lhi * 4];
      float inv[4];
#pragma unroll
      for (int r = 0; r < 4; ++r)
        inv[r] = 1.f / (o_ls[mi][r] + pls[r]);
#pragma unroll
      for (int t = 0; t < 4; ++t) {
        f32x4 po = *(const f32x4*)&Sf[wq * 2048 + (mi * 4 + t) * 256 + lane * 4];
#pragma unroll
        for (int r = 0; r < 4; ++r) {
          size_t ob = ((size_t)n * LSEQ + q0 + wq * 32 + mi * 16 + lhi * 4 + r) * 1024
                    + h * 64 + t * 16 + l15;
          out[ob] = (o[mi][t][r] + po[r]) * inv[r];
        }
      }
    }
  }
#undef STAGE_K
#undef STAGE_V
#undef QK_TILE
#undef SM_TILE
#undef PV_TILE
}

extern "C" void kernel_launch(void* const* d_in, const int* in_sizes, int n_in,
                              void* d_out, int out_size, void* d_ws, size_t ws_size,
                              hipStream_t stream) {
  const float* xv   = (const float*)d_in[0];   // values
  const float* xk   = (const float*)d_in[1];   // keys
  const float* xq   = (const float*)d_in[2];   // queries
  const int*   mask = (const int*)d_in[3];
  const float* Wv   = (const float*)d_in[4];
  const float* Wk   = (const float*)d_in[5];
  const float* Wq   = (const float*)d_in[6];
  float* out = (float*)d_out;

  const size_t elems = (size_t)NB * NH * LSEQ * HD;       // 4,194,304
  __bf16* Qw = (__bf16*)d_ws;
  __bf16* Kw = Qw + elems;
  __bf16* Vw = Kw + elems;          // holds permuted/transposed Vtp layout
  unsigned long long* mb = (unsigned long long*)(Vw + elems);  // 1 MB

  pack_mask_kernel<<<dim3(NB * LSEQ * NKT / 4), 256, 0, stream>>>(mask, mb);
  proj_kernel<<<dim3(64, NH, 3), 256, 0, stream>>>(xv, Wv, xk, Wk, xq, Wq,
                                                   Vw, Kw, Qw);
  attn_kernel<<<dim3(16, 32), 512, 0, stream>>>(Qw, Kw, Vw, mb, out);
}